// Round 1
// baseline (611.885 us; speedup 1.0000x reference)
//
#include <hip/hip_runtime.h>
#include <cmath>

// ---------------------------------------------------------------------------
// GNNPooling: 3x (ChebConv -> BN(train) -> ReLU) -> mean over nodes.
// Key identity: Lhat = alpha*I + beta*J (J=ones), J^2 = 64 J, so
// T_k(Lhat) = a_k I + b_k J and each ChebConv is
//   y[b,n,:] = h[b,n,:] @ (sum_k a_k W_k)  +  (sum_m h[b,m,:]) @ (sum_k b_k W_k)
// ---------------------------------------------------------------------------

constexpr int BATCH = 4096;
constexpr int NODES = 64;
constexpr int CIN1  = 256;
constexpr int DCH   = 128;
constexpr float INV_NROWS = 1.0f / (4096.0f * 64.0f);   // 1/262144

// workspace layout (in floats)
constexpr size_t OFF_WI1  = 0;
constexpr size_t OFF_WJ1  = OFF_WI1 + (size_t)CIN1 * DCH;    // 32768
constexpr size_t OFF_WI2  = OFF_WJ1 + (size_t)CIN1 * DCH;    // 65536
constexpr size_t OFF_WJ2  = OFF_WI2 + (size_t)DCH * DCH;     // 81920
constexpr size_t OFF_WI3  = OFF_WJ2 + (size_t)DCH * DCH;     // 98304
constexpr size_t OFF_WJ3  = OFF_WI3 + (size_t)DCH * DCH;     // 114688
constexpr size_t OFF_RAW  = OFF_WJ3 + (size_t)DCH * DCH;     // 131072, 3*256 floats
constexpr size_t OFF_PART = OFF_RAW + 3 * 256;               // 131840, 256*4096 floats
constexpr size_t OFF_Y    = OFF_PART + (size_t)256 * 4096;   // 1180416, 4096*64*128

struct Coeffs { float a[5]; float b[5]; };

// ---------------------------------------------------------------------------
// Effective weights: WI = sum_k a_k W[k], WJ = sum_k b_k W[k]
// ---------------------------------------------------------------------------
__global__ __launch_bounds__(256) void prep_k(const float* __restrict__ W1,
                                              const float* __restrict__ W2,
                                              const float* __restrict__ W3,
                                              float* __restrict__ ws, Coeffs co)
{
  int idx = blockIdx.x * 256 + threadIdx.x;     // 0..65535
  if (idx < 32768) {
    float si = 0.f, sj = 0.f;
#pragma unroll
    for (int k = 0; k < 5; ++k) {
      float w = W1[k * 32768 + idx];
      si = fmaf(co.a[k], w, si);
      sj = fmaf(co.b[k], w, sj);
    }
    ws[OFF_WI1 + idx] = si;
    ws[OFF_WJ1 + idx] = sj;
  } else if (idx < 49152) {
    int e = idx - 32768;
    float si = 0.f, sj = 0.f;
#pragma unroll
    for (int k = 0; k < 3; ++k) {
      float w = W2[k * 16384 + e];
      si = fmaf(co.a[k], w, si);
      sj = fmaf(co.b[k], w, sj);
    }
    ws[OFF_WI2 + e] = si;
    ws[OFF_WJ2 + e] = sj;
  } else {
    int e = idx - 49152;
    float si = 0.f, sj = 0.f;
#pragma unroll
    for (int k = 0; k < 3; ++k) {
      float w = W3[k * 16384 + e];
      si = fmaf(co.a[k], w, si);
      sj = fmaf(co.b[k], w, sj);
    }
    ws[OFF_WI3 + e] = si;
    ws[OFF_WJ3 + e] = sj;
  }
}

// ---------------------------------------------------------------------------
// One fused layer: (optional BN+ReLU of input) -> y = h@WI + (1*s)@WJ,
// writes y and per-block BN partial sums (transposed layout part[stat][block]).
// One block = one batch element (64 nodes). In-place (in==yout) is safe:
// all reads of in[b] happen in the staging phases, all writes after the K-loop.
// ---------------------------------------------------------------------------
template <int CIN, bool FIRST>
__global__ __launch_bounds__(256) void layer_k(
    const float* __restrict__ in, float* __restrict__ yout,
    const float* __restrict__ WI, const float* __restrict__ WJ,
    const float* __restrict__ raw, const float* __restrict__ gam,
    const float* __restrict__ bet, float* __restrict__ part)
{
  constexpr int BK = 64;
  constexpr int NCHUNK = CIN / BK;

  __shared__ float sA[NODES][BK + 4];                 // 64 x 68, pad -> A reads 2-way broadcast
  __shared__ union UW {
    float w[BK][DCH + 4];                             // 64 x 132 (16B-aligned rows)
    struct { float sum[DCH][17]; float sq[DCH][17]; } red;
  } uW;
  __shared__ float sS[CIN];                           // per-batch feature sums
  __shared__ float sScale[DCH];
  __shared__ float sShift[DCH];
  __shared__ union UP {
    float p[4][64];                                   // column-sum partials
    float jh[2][DCH];                                 // J-term halves
  } uP;

  const int tid = threadIdx.x;
  const int b   = blockIdx.x;
  const float* __restrict__ inb = in + (size_t)b * (NODES * CIN);

  if constexpr (!FIRST) {
    if (tid < DCH) {
      float mu  = raw[tid] * INV_NROWS;
      float var = raw[DCH + tid] * INV_NROWS - mu * mu;
      float rs  = rsqrtf(var + 1e-5f);
      float sc  = gam[tid] * rs;
      sScale[tid] = sc;
      sShift[tid] = fmaf(-mu, sc, bet[tid]);
    }
    __syncthreads();
  }

  const int tr  = tid >> 4;     // 0..15 (4 rows each)
  const int tc  = tid & 15;     // 0..15 (8 cols each)
  const int tc8 = tc * 8;

  float acc[4][8];
#pragma unroll
  for (int i = 0; i < 4; ++i)
#pragma unroll
    for (int j = 0; j < 8; ++j) acc[i][j] = 0.f;

  for (int ck = 0; ck < NCHUNK; ++ck) {
    const int f0 = ck * BK;
    // ---- stage A tile: 64 rows x 64 features (apply BN+ReLU if !FIRST) ----
#pragma unroll
    for (int i = 0; i < 4; ++i) {
      int idx = tid + i * 256;          // 0..1023
      int row = idx >> 4;
      int f4  = idx & 15;
      float4 v = *reinterpret_cast<const float4*>(inb + (size_t)row * CIN + f0 + f4 * 4);
      if constexpr (!FIRST) {
        int ch = f0 + f4 * 4;
        v.x = fmaxf(fmaf(v.x, sScale[ch + 0], sShift[ch + 0]), 0.f);
        v.y = fmaxf(fmaf(v.y, sScale[ch + 1], sShift[ch + 1]), 0.f);
        v.z = fmaxf(fmaf(v.z, sScale[ch + 2], sShift[ch + 2]), 0.f);
        v.w = fmaxf(fmaf(v.w, sScale[ch + 3], sShift[ch + 3]), 0.f);
      }
      *reinterpret_cast<float4*>(&sA[row][f4 * 4]) = v;
    }
    // ---- stage W tile: 64 x 128 ----
#pragma unroll
    for (int i = 0; i < 8; ++i) {
      int idx = tid + i * 256;          // 0..2047
      int row = idx >> 5;
      int c4  = idx & 31;
      float4 v = *reinterpret_cast<const float4*>(WI + (size_t)(f0 + row) * DCH + c4 * 4);
      *reinterpret_cast<float4*>(&uW.w[row][c4 * 4]) = v;
    }
    __syncthreads();

    // ---- column partial sums of A for the J term ----
    {
      int f = tid & 63;
      int q = tid >> 6;
      float p = 0.f;
#pragma unroll
      for (int r = 0; r < 16; ++r) p += sA[q * 16 + r][f];
      uP.p[q][f] = p;
    }
    __syncthreads();
    if (tid < 64)
      sS[f0 + tid] = uP.p[0][tid] + uP.p[1][tid] + uP.p[2][tid] + uP.p[3][tid];

    // ---- GEMM on the tile: acc += A(64x64) * W(64x128), 4x8 per thread ----
    const float* pa0 = &sA[tr * 4 + 0][0];
    const float* pa1 = &sA[tr * 4 + 1][0];
    const float* pa2 = &sA[tr * 4 + 2][0];
    const float* pa3 = &sA[tr * 4 + 3][0];
#pragma unroll 4
    for (int k = 0; k < BK; k += 4) {
      float af[4][4];
      *reinterpret_cast<float4*>(af[0]) = *reinterpret_cast<const float4*>(pa0 + k);
      *reinterpret_cast<float4*>(af[1]) = *reinterpret_cast<const float4*>(pa1 + k);
      *reinterpret_cast<float4*>(af[2]) = *reinterpret_cast<const float4*>(pa2 + k);
      *reinterpret_cast<float4*>(af[3]) = *reinterpret_cast<const float4*>(pa3 + k);
#pragma unroll
      for (int kk = 0; kk < 4; ++kk) {
        const float* wrow = &uW.w[k + kk][tc8];
        float4 w0 = *reinterpret_cast<const float4*>(wrow);
        float4 w1 = *reinterpret_cast<const float4*>(wrow + 4);
        float wv[8] = {w0.x, w0.y, w0.z, w0.w, w1.x, w1.y, w1.z, w1.w};
#pragma unroll
        for (int i = 0; i < 4; ++i)
#pragma unroll
          for (int j = 0; j < 8; ++j)
            acc[i][j] = fmaf(af[i][kk], wv[j], acc[i][j]);
      }
    }
    __syncthreads();
  }

  // ---- J term: j[o] = sum_f sS[f] * WJ[f][o], split over two thread halves ----
  {
    const int o    = tid & (DCH - 1);
    const int half = tid >> 7;
    const int F0   = half * (CIN / 2);
    float j0 = 0.f, j1 = 0.f;
#pragma unroll 4
    for (int f = F0; f < F0 + CIN / 2; f += 2) {
      j0 = fmaf(sS[f],     WJ[(size_t)f * DCH + o],       j0);
      j1 = fmaf(sS[f + 1], WJ[(size_t)(f + 1) * DCH + o], j1);
    }
    uP.jh[half][o] = j0 + j1;
  }
  __syncthreads();

  float jv[8];
#pragma unroll
  for (int j = 0; j < 8; ++j) jv[j] = uP.jh[0][tc8 + j] + uP.jh[1][tc8 + j];

  // ---- write y and accumulate BN partials ----
  float psum[8], psq[8];
#pragma unroll
  for (int j = 0; j < 8; ++j) { psum[j] = 0.f; psq[j] = 0.f; }

  float* __restrict__ yb = yout + (size_t)b * (NODES * DCH);
#pragma unroll
  for (int i = 0; i < 4; ++i) {
    int row = tr * 4 + i;
    float v[8];
#pragma unroll
    for (int j = 0; j < 8; ++j) {
      float t = acc[i][j] + jv[j];
      v[j] = t;
      psum[j] += t;
      psq[j]  = fmaf(t, t, psq[j]);
    }
    float4* dst = reinterpret_cast<float4*>(yb + (size_t)row * DCH + tc8);
    dst[0] = make_float4(v[0], v[1], v[2], v[3]);
    dst[1] = make_float4(v[4], v[5], v[6], v[7]);
  }

  // block reduction of BN partials (reuse uW; all tile reads are behind syncs)
#pragma unroll
  for (int j = 0; j < 8; ++j) {
    uW.red.sum[tc8 + j][tr] = psum[j];
    uW.red.sq [tc8 + j][tr] = psq[j];
  }
  __syncthreads();
  {
    const int o = tid & (DCH - 1);
    float tot = 0.f;
    if (tid < DCH) {
#pragma unroll
      for (int t = 0; t < 16; ++t) tot += uW.red.sum[o][t];
    } else {
#pragma unroll
      for (int t = 0; t < 16; ++t) tot += uW.red.sq[o][t];
    }
    part[(size_t)tid * BATCH + b] = tot;   // transposed: part[stat][block]
  }
}

// ---------------------------------------------------------------------------
// Reduce partials: raw[j] = sum_b part[j][b]  (j<128 -> sum, j>=128 -> sumsq)
// ---------------------------------------------------------------------------
__global__ __launch_bounds__(256) void finalize_k(const float* __restrict__ part,
                                                  float* __restrict__ raw)
{
  __shared__ float red[256];
  const int j = blockIdx.x;
  float s = 0.f;
  for (int i = threadIdx.x; i < BATCH; i += 256)
    s += part[(size_t)j * BATCH + i];
  red[threadIdx.x] = s;
  __syncthreads();
  for (int st = 128; st > 0; st >>= 1) {
    if (threadIdx.x < st) red[threadIdx.x] += red[threadIdx.x + st];
    __syncthreads();
  }
  if (threadIdx.x == 0) raw[j] = red[0];
}

// ---------------------------------------------------------------------------
// Final BN + ReLU + mean over nodes
// ---------------------------------------------------------------------------
__global__ __launch_bounds__(128) void pool_k(const float* __restrict__ y,
                                              const float* __restrict__ raw,
                                              const float* __restrict__ gam,
                                              const float* __restrict__ bet,
                                              float* __restrict__ out)
{
  const int b = blockIdx.x;
  const int t = threadIdx.x;
  float mu  = raw[t] * INV_NROWS;
  float var = raw[DCH + t] * INV_NROWS - mu * mu;
  float rs  = rsqrtf(var + 1e-5f);
  float sc  = gam[t] * rs;
  float sh  = fmaf(-mu, sc, bet[t]);
  const float* yb = y + (size_t)b * (NODES * DCH);
  float acc = 0.f;
#pragma unroll 8
  for (int n = 0; n < NODES; ++n)
    acc += fmaxf(fmaf(yb[(size_t)n * DCH + t], sc, sh), 0.f);
  out[(size_t)b * DCH + t] = acc * (1.0f / 64.0f);
}

// ---------------------------------------------------------------------------
extern "C" void kernel_launch(void* const* d_in, const int* in_sizes, int n_in,
                              void* d_out, int out_size, void* d_ws, size_t ws_size,
                              hipStream_t stream)
{
  const float* x  = (const float*)d_in[0];
  const float* W1 = (const float*)d_in[1];
  const float* W2 = (const float*)d_in[2];
  const float* W3 = (const float*)d_in[3];
  const float* g1 = (const float*)d_in[4];
  const float* b1 = (const float*)d_in[5];
  const float* g2 = (const float*)d_in[6];
  const float* b2 = (const float*)d_in[7];
  const float* g3 = (const float*)d_in[8];
  const float* b3 = (const float*)d_in[9];
  float* out = (float*)d_out;
  float* ws  = (float*)d_ws;

  // Chebyshev coefficients of Lhat = alpha*I + beta*J  (host, double precision)
  Coeffs co;
  {
    double sd  = sqrt(63.0 / 4095.0);        // std of (ones-eye), ddof=1
    double av  = exp(-1.0 / sd);             // off-diagonal of A
    double deg = 1.0 + 63.0 * av;
    double al  = -(1.0 - av) / deg;
    double be  = -av / deg;
    double ak[5], bk[5];
    ak[0] = 1.0; bk[0] = 0.0;
    ak[1] = al;  bk[1] = be;
    for (int k = 2; k < 5; ++k) {
      ak[k] = 2.0 * al * ak[k - 1] - ak[k - 2];
      bk[k] = 2.0 * (be * ak[k - 1] + (al + 64.0 * be) * bk[k - 1]) - bk[k - 2];
    }
    for (int k = 0; k < 5; ++k) { co.a[k] = (float)ak[k]; co.b[k] = (float)bk[k]; }
  }

  float* WI1  = ws + OFF_WI1;
  float* WJ1  = ws + OFF_WJ1;
  float* WI2  = ws + OFF_WI2;
  float* WJ2  = ws + OFF_WJ2;
  float* WI3  = ws + OFF_WI3;
  float* WJ3  = ws + OFF_WJ3;
  float* raw1 = ws + OFF_RAW;
  float* raw2 = raw1 + 256;
  float* raw3 = raw1 + 512;
  float* pp   = ws + OFF_PART;
  float* yv   = ws + OFF_Y;

  prep_k<<<256, 256, 0, stream>>>(W1, W2, W3, ws, co);
  layer_k<256, true ><<<BATCH, 256, 0, stream>>>(x,  yv, WI1, WJ1, nullptr, nullptr, nullptr, pp);
  finalize_k<<<256, 256, 0, stream>>>(pp, raw1);
  layer_k<128, false><<<BATCH, 256, 0, stream>>>(yv, yv, WI2, WJ2, raw1, g1, b1, pp);
  finalize_k<<<256, 256, 0, stream>>>(pp, raw2);
  layer_k<128, false><<<BATCH, 256, 0, stream>>>(yv, yv, WI3, WJ3, raw2, g2, b2, pp);
  finalize_k<<<256, 256, 0, stream>>>(pp, raw3);
  pool_k<<<BATCH, 128, 0, stream>>>(yv, raw3, g3, b3, out);

  (void)in_sizes; (void)n_in; (void)out_size; (void)ws_size;
}

// Round 2
// 293.638 us; speedup vs baseline: 2.0838x; 2.0838x over previous
//
#include <hip/hip_runtime.h>
#include <cmath>

// ---------------------------------------------------------------------------
// GNNPooling: 3x (ChebConv -> BN(train) -> ReLU) -> mean over nodes.
// Lhat = alpha*I + beta*J  =>  y[b] = A_b @ WI + 1 * (colsum(A_b) @ WJ)
// GEMM via mfma_f32_16x16x32_bf16; A loaded in fragment order from global
// (y stored pre-swizzled bf16 granules); W pre-swizzled into B-frag granules.
// ---------------------------------------------------------------------------

typedef __attribute__((ext_vector_type(8))) short bf16x8;
typedef __attribute__((ext_vector_type(4))) float f32x4;

constexpr int BATCH = 4096;
constexpr int DCH   = 128;
constexpr float INV_NROWS = 1.0f / 262144.0f;

// workspace offsets (in floats)
constexpr size_t OFF_GW1I = 0;            // 4096 granules * 16B = 16384 floats
constexpr size_t OFF_GW2I = 16384;        // 2048 granules -> 8192 floats
constexpr size_t OFF_GW3I = 24576;        // 8192 floats
constexpr size_t OFF_WJ1F = 32768;        // fp32 row-major 256x128
constexpr size_t OFF_WJ2F = 65536;        // 128x128
constexpr size_t OFF_WJ3F = 81920;        // 128x128
constexpr size_t OFF_RAW  = 98304;        // 3*256
constexpr size_t OFF_PART = 99072;        // 256*4096
constexpr size_t OFF_Y    = 1147648;      // y bf16: 4096*64*128 ushorts

struct Coeffs { float a[5]; float b[5]; };

__device__ __forceinline__ unsigned short f2bf(float f) {
  unsigned u = __float_as_uint(f);
  u += 0x7FFFu + ((u >> 16) & 1u);        // round-to-nearest-even
  return (unsigned short)(u >> 16);
}
__device__ __forceinline__ float bf2f(unsigned short s) {
  return __uint_as_float(((unsigned)s) << 16);
}

// ---------------------------------------------------------------------------
// prep_gran: build WI (= sum_k a_k W_k) in B-fragment granule order, bf16.
// granule r = kt*512 + ct*64 + lane ; value_i = WI[kt*32+(lane>>4)*8+i][ct*16+(lane&15)]
// ---------------------------------------------------------------------------
__device__ __forceinline__ void gather8(const float* __restrict__ W, int CIN, int K,
                                        const float* cf, int f0, int col,
                                        unsigned short* dst) {
  bf16x8 g;
#pragma unroll
  for (int i = 0; i < 8; ++i) {
    float s = 0.f;
    if (K == 5) {
#pragma unroll
      for (int k = 0; k < 5; ++k)
        s = fmaf(cf[k], W[((size_t)k * CIN + f0 + i) * DCH + col], s);
    } else {
#pragma unroll
      for (int k = 0; k < 3; ++k)
        s = fmaf(cf[k], W[((size_t)k * CIN + f0 + i) * DCH + col], s);
    }
    g[i] = (short)f2bf(s);
  }
  *reinterpret_cast<bf16x8*>(dst) = g;
}

__global__ __launch_bounds__(256) void prep_gran(const float* __restrict__ W1,
                                                 const float* __restrict__ W2,
                                                 const float* __restrict__ W3,
                                                 float* __restrict__ ws, Coeffs co)
{
  int id = blockIdx.x * 256 + threadIdx.x;       // 0..8191
  const float* W; int CIN, K; unsigned short* dst; int r;
  if (id < 4096)      { W = W1; CIN = 256; K = 5; r = id;        dst = (unsigned short*)(ws + OFF_GW1I); }
  else if (id < 6144) { W = W2; CIN = 128; K = 3; r = id - 4096; dst = (unsigned short*)(ws + OFF_GW2I); }
  else                { W = W3; CIN = 128; K = 3; r = id - 6144; dst = (unsigned short*)(ws + OFF_GW3I); }
  int kt = r >> 9;
  int ct = (r >> 6) & 7;
  int ln = r & 63;
  int col = ct * 16 + (ln & 15);
  int f0  = kt * 32 + (ln >> 4) * 8;
  gather8(W, CIN, K, co.a, f0, col, dst + (size_t)r * 8);
}

// WJ in fp32 row-major (for the per-block J GEMV)
__global__ __launch_bounds__(256) void prep_wj(const float* __restrict__ W1,
                                               const float* __restrict__ W2,
                                               const float* __restrict__ W3,
                                               float* __restrict__ ws, Coeffs co)
{
  int id = blockIdx.x * 256 + threadIdx.x;       // 0..65535
  if (id < 32768) {
    int f = id >> 7, o = id & 127;
    float s = 0.f;
#pragma unroll
    for (int k = 0; k < 5; ++k) s = fmaf(co.b[k], W1[((size_t)k * 256 + f) * DCH + o], s);
    ws[OFF_WJ1F + id] = s;
  } else if (id < 49152) {
    int e = id - 32768, f = e >> 7, o = e & 127;
    float s = 0.f;
#pragma unroll
    for (int k = 0; k < 3; ++k) s = fmaf(co.b[k], W2[((size_t)k * 128 + f) * DCH + o], s);
    ws[OFF_WJ2F + e] = s;
  } else {
    int e = id - 49152, f = e >> 7, o = e & 127;
    float s = 0.f;
#pragma unroll
    for (int k = 0; k < 3; ++k) s = fmaf(co.b[k], W3[((size_t)k * 128 + f) * DCH + o], s);
    ws[OFF_WJ3F + e] = s;
  }
}

// ---------------------------------------------------------------------------
// Fused layer. Block = one batch (64 nodes x 128 outputs), 4 waves.
// Wave w owns rows w*16..w*16+15. MFMA 16x16x32 bf16, acc per wave: 8 n-tiles.
// ---------------------------------------------------------------------------
template <int CIN, bool FIRST>
__global__ __launch_bounds__(256) void layer_k(
    const float* __restrict__ inF,              // FIRST: x (row-major fp32)
    const unsigned short* __restrict__ inB,     // !FIRST: y bf16 granules
    unsigned short* __restrict__ yout,          // y bf16 granules
    const unsigned short* __restrict__ gWI,     // WI b-frag granules bf16
    const float* __restrict__ WJf,              // WJ fp32 row-major CIN x 128
    const float* __restrict__ raw, const float* __restrict__ gam,
    const float* __restrict__ bet, float* __restrict__ part)
{
  constexpr int NKT = CIN / 32;

  __shared__ float sS4[4][CIN];        // per-wave column-sum partials
  __shared__ float sJh[2][DCH];        // J GEMV halves
  __shared__ float sScale[DCH];
  __shared__ float sShift[DCH];
  __shared__ float sY[64][68];         // epilogue transpose (column half) / sRed union

  const int tid = threadIdx.x;
  const int w  = tid >> 6;
  const int l  = tid & 63;
  const int lr = l & 15;               // A-row within stripe / D-col within tile
  const int lk = l >> 4;               // k-slot
  const int b  = blockIdx.x;

  if constexpr (!FIRST) {
    if (tid < DCH) {
      float mu  = raw[tid] * INV_NROWS;
      float var = raw[DCH + tid] * INV_NROWS - mu * mu;
      float rs  = rsqrtf(var + 1e-5f);
      float sc  = gam[tid] * rs;
      sScale[tid] = sc;
      sShift[tid] = fmaf(-mu, sc, bet[tid]);
    }
    __syncthreads();
  }

  f32x4 acc[8];
#pragma unroll
  for (int ct = 0; ct < 8; ++ct)
#pragma unroll
    for (int r = 0; r < 4; ++r) acc[ct][r] = 0.f;

  for (int kt = 0; kt < NKT; ++kt) {
    float v[8];
    if constexpr (FIRST) {
      const float* p = inF + ((size_t)(b * 64 + w * 16 + lr)) * CIN + kt * 32 + lk * 8;
      float4 u0 = *reinterpret_cast<const float4*>(p);
      float4 u1 = *reinterpret_cast<const float4*>(p + 4);
      v[0] = u0.x; v[1] = u0.y; v[2] = u0.z; v[3] = u0.w;
      v[4] = u1.x; v[5] = u1.y; v[6] = u1.z; v[7] = u1.w;
    } else {
      bf16x8 r16 = *(reinterpret_cast<const bf16x8*>(inB + (size_t)b * 8192) +
                     (kt * 256 + w * 64 + l));
      const float4 sc0 = *reinterpret_cast<const float4*>(&sScale[kt * 32 + lk * 8]);
      const float4 sc1 = *reinterpret_cast<const float4*>(&sScale[kt * 32 + lk * 8 + 4]);
      const float4 sh0 = *reinterpret_cast<const float4*>(&sShift[kt * 32 + lk * 8]);
      const float4 sh1 = *reinterpret_cast<const float4*>(&sShift[kt * 32 + lk * 8 + 4]);
      const float scv[8] = {sc0.x, sc0.y, sc0.z, sc0.w, sc1.x, sc1.y, sc1.z, sc1.w};
      const float shv[8] = {sh0.x, sh0.y, sh0.z, sh0.w, sh1.x, sh1.y, sh1.z, sh1.w};
#pragma unroll
      for (int i = 0; i < 8; ++i)
        v[i] = fmaxf(fmaf(bf2f((unsigned short)r16[i]), scv[i], shv[i]), 0.f);
    }

    bf16x8 afrag;
#pragma unroll
    for (int i = 0; i < 8; ++i) afrag[i] = (short)f2bf(v[i]);

    // column sums over the wave's 16 rows (butterfly within 16-lane groups)
#pragma unroll
    for (int i = 0; i < 8; ++i) v[i] += __shfl_xor(v[i], 1, 16);
#pragma unroll
    for (int i = 0; i < 8; ++i) v[i] += __shfl_xor(v[i], 2, 16);
#pragma unroll
    for (int i = 0; i < 8; ++i) v[i] += __shfl_xor(v[i], 4, 16);
#pragma unroll
    for (int i = 0; i < 8; ++i) v[i] += __shfl_xor(v[i], 8, 16);
    float sel = v[0];
    sel = (lr == 1) ? v[1] : sel;
    sel = (lr == 2) ? v[2] : sel;
    sel = (lr == 3) ? v[3] : sel;
    sel = (lr == 4) ? v[4] : sel;
    sel = (lr == 5) ? v[5] : sel;
    sel = (lr == 6) ? v[6] : sel;
    sel = (lr == 7) ? v[7] : sel;
    if (lr < 8) sS4[w][kt * 32 + lk * 8 + lr] = sel;

    // 8 MFMAs against pre-swizzled B granules (L2-resident)
    const bf16x8* gw = reinterpret_cast<const bf16x8*>(gWI) + kt * 512 + l;
#pragma unroll
    for (int ct = 0; ct < 8; ++ct) {
      bf16x8 bfrag = gw[ct * 64];
      acc[ct] = __builtin_amdgcn_mfma_f32_16x16x32_bf16(afrag, bfrag, acc[ct], 0, 0, 0);
    }
  }
  __syncthreads();

  // J GEMV: jrow[o] = sum_f s[f] * WJ[f][o]
  {
    const int o = tid & 127, half = tid >> 7;
    float j = 0.f;
#pragma unroll 4
    for (int f = half * (CIN / 2); f < (half + 1) * (CIN / 2); ++f) {
      float s = sS4[0][f] + sS4[1][f] + sS4[2][f] + sS4[3][f];
      j = fmaf(s, WJf[(size_t)f * DCH + o], j);
    }
    sJh[half][o] = j;
  }
  __syncthreads();

  // epilogue: add J, BN partials from regs, transpose via LDS (two column halves),
  // store bf16 granules for the next layer's fragment-order loads.
  float psum[8], psq[8];
#pragma unroll
  for (int ct = 0; ct < 8; ++ct) { psum[ct] = 0.f; psq[ct] = 0.f; }

#pragma unroll
  for (int cp = 0; cp < 2; ++cp) {
#pragma unroll
    for (int cc = 0; cc < 4; ++cc) {
      const int ct = cp * 4 + cc;
      const float jv = sJh[0][ct * 16 + lr] + sJh[1][ct * 16 + lr];
#pragma unroll
      for (int r = 0; r < 4; ++r) {
        float val = acc[ct][r] + jv;
        psum[ct] += val;
        psq[ct]  = fmaf(val, val, psq[ct]);
        sY[w * 16 + lk * 4 + r][cc * 16 + lr] = val;
      }
    }
    __syncthreads();
#pragma unroll
    for (int k2 = 0; k2 < 2; ++k2) {
      const float* pr = &sY[w * 16 + lr][k2 * 32 + lk * 8];
      float4 a0 = *reinterpret_cast<const float4*>(pr);
      float4 a1 = *reinterpret_cast<const float4*>(pr + 4);
      float vals[8] = {a0.x, a0.y, a0.z, a0.w, a1.x, a1.y, a1.z, a1.w};
      bf16x8 st;
#pragma unroll
      for (int i = 0; i < 8; ++i) st[i] = (short)f2bf(vals[i]);
      *(reinterpret_cast<bf16x8*>(yout + (size_t)b * 8192) +
        ((cp * 2 + k2) * 256 + w * 64 + l)) = st;
    }
    __syncthreads();
  }

  // BN partial reduction (union sRed over sY: 64*68 = 2*128*17 floats)
  float* sRedS = &sY[0][0];
  float* sRedQ = sRedS + 128 * 17;
#pragma unroll
  for (int ct = 0; ct < 8; ++ct) {
    sRedS[(ct * 16 + lr) * 17 + (w * 4 + lk)] = psum[ct];
    sRedQ[(ct * 16 + lr) * 17 + (w * 4 + lk)] = psq[ct];
  }
  __syncthreads();
  {
    const int c = tid & 127;
    const float* src = (tid >> 7) ? sRedQ : sRedS;
    float tot = 0.f;
#pragma unroll
    for (int p = 0; p < 16; ++p) tot += src[c * 17 + p];
    part[(size_t)tid * BATCH + b] = tot;
  }
}

// ---------------------------------------------------------------------------
__global__ __launch_bounds__(256) void finalize_k(const float* __restrict__ part,
                                                  float* __restrict__ raw)
{
  __shared__ float red[256];
  const int j = blockIdx.x;
  float s = 0.f;
  for (int i = threadIdx.x; i < BATCH; i += 256)
    s += part[(size_t)j * BATCH + i];
  red[threadIdx.x] = s;
  __syncthreads();
  for (int st = 128; st > 0; st >>= 1) {
    if (threadIdx.x < st) red[threadIdx.x] += red[threadIdx.x + st];
    __syncthreads();
  }
  if (threadIdx.x == 0) raw[j] = red[0];
}

// ---------------------------------------------------------------------------
// Final BN + ReLU + mean over nodes (reads bf16 granules)
// ---------------------------------------------------------------------------
__global__ __launch_bounds__(256) void pool_k(const unsigned short* __restrict__ y,
                                              const float* __restrict__ raw,
                                              const float* __restrict__ gam,
                                              const float* __restrict__ bet,
                                              float* __restrict__ out)
{
  __shared__ float sYp[64][132];
  __shared__ float sPool[2][DCH];
  const int b = blockIdx.x;
  const int t = threadIdx.x;
  const int wv = t >> 6, l = t & 63;
  const int row = wv * 16 + (l & 15);

#pragma unroll
  for (int kt = 0; kt < 4; ++kt) {
    bf16x8 r16 = *(reinterpret_cast<const bf16x8*>(y + (size_t)b * 8192) + (kt * 256 + t));
    const int feat = kt * 32 + (l >> 4) * 8;
    float4 f0, f1;
    f0.x = bf2f((unsigned short)r16[0]); f0.y = bf2f((unsigned short)r16[1]);
    f0.z = bf2f((unsigned short)r16[2]); f0.w = bf2f((unsigned short)r16[3]);
    f1.x = bf2f((unsigned short)r16[4]); f1.y = bf2f((unsigned short)r16[5]);
    f1.z = bf2f((unsigned short)r16[6]); f1.w = bf2f((unsigned short)r16[7]);
    *reinterpret_cast<float4*>(&sYp[row][feat])     = f0;
    *reinterpret_cast<float4*>(&sYp[row][feat + 4]) = f1;
  }
  __syncthreads();
  {
    const int c = t & 127, rg = t >> 7;
    float mu  = raw[c] * INV_NROWS;
    float var = raw[DCH + c] * INV_NROWS - mu * mu;
    float rs  = rsqrtf(var + 1e-5f);
    float sc  = gam[c] * rs;
    float sh  = fmaf(-mu, sc, bet[c]);
    float s = 0.f;
#pragma unroll 8
    for (int r = rg * 32; r < rg * 32 + 32; ++r)
      s += fmaxf(fmaf(sYp[r][c], sc, sh), 0.f);
    sPool[rg][c] = s;
  }
  __syncthreads();
  if (t < DCH)
    out[(size_t)b * DCH + t] = (sPool[0][t] + sPool[1][t]) * (1.0f / 64.0f);
}

// ---------------------------------------------------------------------------
extern "C" void kernel_launch(void* const* d_in, const int* in_sizes, int n_in,
                              void* d_out, int out_size, void* d_ws, size_t ws_size,
                              hipStream_t stream)
{
  const float* x  = (const float*)d_in[0];
  const float* W1 = (const float*)d_in[1];
  const float* W2 = (const float*)d_in[2];
  const float* W3 = (const float*)d_in[3];
  const float* g1 = (const float*)d_in[4];
  const float* b1 = (const float*)d_in[5];
  const float* g2 = (const float*)d_in[6];
  const float* b2 = (const float*)d_in[7];
  const float* g3 = (const float*)d_in[8];
  const float* b3 = (const float*)d_in[9];
  float* out = (float*)d_out;
  float* ws  = (float*)d_ws;

  Coeffs co;
  {
    double sd  = sqrt(63.0 / 4095.0);
    double av  = exp(-1.0 / sd);
    double deg = 1.0 + 63.0 * av;
    double al  = -(1.0 - av) / deg;
    double be  = -av / deg;
    double ak[5], bk[5];
    ak[0] = 1.0; bk[0] = 0.0;
    ak[1] = al;  bk[1] = be;
    for (int k = 2; k < 5; ++k) {
      ak[k] = 2.0 * al * ak[k - 1] - ak[k - 2];
      bk[k] = 2.0 * (be * ak[k - 1] + (al + 64.0 * be) * bk[k - 1]) - bk[k - 2];
    }
    for (int k = 0; k < 5; ++k) { co.a[k] = (float)ak[k]; co.b[k] = (float)bk[k]; }
  }

  const unsigned short* gw1 = (const unsigned short*)(ws + OFF_GW1I);
  const unsigned short* gw2 = (const unsigned short*)(ws + OFF_GW2I);
  const unsigned short* gw3 = (const unsigned short*)(ws + OFF_GW3I);
  const float* wj1 = ws + OFF_WJ1F;
  const float* wj2 = ws + OFF_WJ2F;
  const float* wj3 = ws + OFF_WJ3F;
  float* raw1 = ws + OFF_RAW;
  float* raw2 = raw1 + 256;
  float* raw3 = raw1 + 512;
  float* pp   = ws + OFF_PART;
  unsigned short* yv = (unsigned short*)(ws + OFF_Y);

  prep_gran<<<32, 256, 0, stream>>>(W1, W2, W3, ws, co);
  prep_wj<<<256, 256, 0, stream>>>(W1, W2, W3, ws, co);

  layer_k<256, true ><<<BATCH, 256, 0, stream>>>(x, nullptr, yv, gw1, wj1,
                                                 nullptr, nullptr, nullptr, pp);
  finalize_k<<<256, 256, 0, stream>>>(pp, raw1);
  layer_k<128, false><<<BATCH, 256, 0, stream>>>(nullptr, yv, yv, gw2, wj2,
                                                 raw1, g1, b1, pp);
  finalize_k<<<256, 256, 0, stream>>>(pp, raw2);
  layer_k<128, false><<<BATCH, 256, 0, stream>>>(nullptr, yv, yv, gw3, wj3,
                                                 raw2, g2, b2, pp);
  finalize_k<<<256, 256, 0, stream>>>(pp, raw3);
  pool_k<<<BATCH, 256, 0, stream>>>(yv, raw3, g3, b3, out);

  (void)in_sizes; (void)n_in; (void)out_size; (void)ws_size;
}